// Round 1
// baseline (1748.289 us; speedup 1.0000x reference)
//
#include <hip/hip_runtime.h>
#include <math.h>

#define BB 2
#define CCH 64
#define HH 128
#define WWD 128
#define HWv (HH*WWD)
#define KK 9

// ---------------- conv 1x1 : x0 = w0 @ x + b0 ----------------
__global__ __launch_bounds__(256) void conv1x1_k(const float* __restrict__ x,
    const float* __restrict__ w0, const float* __restrict__ b0,
    float* __restrict__ x0) {
  int idx = blockIdx.x * 256 + threadIdx.x;           // over B*C*HW
  int hw = idx & (HWv - 1);
  int co = (idx >> 14) & 63;
  int b  = idx >> 20;
  const float* xin  = x + (size_t)b * CCH * HWv + hw;
  const float* wrow = w0 + co * CCH;
  float acc = b0[co];
  #pragma unroll
  for (int ci = 0; ci < CCH; ci++)
    acc = fmaf(wrow[ci], xin[ci * HWv], acc);
  x0[idx] = acc;
}

// ---------------- conv 3x3, 128ch in (concat x0,y), 27ch out ----------------
__global__ __launch_bounds__(256) void conv_om_k(const float* __restrict__ x0,
    const float* __restrict__ y, const float* __restrict__ w_om,
    const float* __restrict__ b_om, float* __restrict__ om) {
  int idx = blockIdx.x * 256 + threadIdx.x;           // over B*27*HW
  if (idx >= BB * 27 * HWv) return;
  int hw = idx & (HWv - 1);
  int co = (idx >> 14) % 27;
  int b  = idx / (27 * HWv);
  int h = hw >> 7, w = hw & 127;
  float acc = b_om[co];
  const float* wb = w_om + co * 128 * 9;
  for (int ci = 0; ci < 128; ci++) {
    const float* src = (ci < CCH) ? (x0 + ((size_t)b * CCH + ci) * HWv)
                                  : (y  + ((size_t)b * CCH + (ci - CCH)) * HWv);
    const float* wk = wb + ci * 9;
    #pragma unroll
    for (int dy = 0; dy < 3; dy++) {
      int hh = h - 1 + dy;
      if ((unsigned)hh >= HH) continue;
      #pragma unroll
      for (int dx = 0; dx < 3; dx++) {
        int ww = w - 1 + dx;
        if ((unsigned)ww >= WWD) continue;
        acc = fmaf(wk[dy * 3 + dx], src[hh * WWD + ww], acc);
      }
    }
  }
  om[idx] = acc;
}

// ---------------- deformable conv + residual x0 ----------------
// block = 256 threads = 4 pixels x 64 channels. Phase 1: each thread (pixel,ci)
// computes 9 bilinear samples of y (pre-multiplied by mask) into LDS.
// Phase 2: thread (pixel,co) does 576-MAC dot with w_dc, adds x0 + b_dc.
__global__ __launch_bounds__(256) void deform_k(const float* __restrict__ y,
    const float* __restrict__ om, const float* __restrict__ x0,
    const float* __restrict__ w_dc, const float* __restrict__ b_dc,
    float* __restrict__ outp) {
  __shared__ float samp[4][CCH * KK];                 // 4*576 floats = 9.2 KB
  int lp = threadIdx.x >> 6;                          // local pixel 0..3
  int ci = threadIdx.x & 63;
  int pix = blockIdx.x * 4 + lp;                      // over B*HW
  int hw = pix & (HWv - 1);
  int b  = pix >> 14;
  int h = hw >> 7, w = hw & 127;
  const float* ombase = om + (size_t)b * 27 * HWv + hw;
  const float* ysrc   = y + ((size_t)b * CCH + ci) * HWv;
  float* sl = samp[lp];
  #pragma unroll
  for (int k = 0; k < KK; k++) {
    float dy = ombase[(2 * k) * HWv];
    float dx = ombase[(2 * k + 1) * HWv];
    float mk = 2.f / (1.f + expf(-ombase[(18 + k) * HWv]));
    float ys = (float)(h - 1 + k / 3) + dy;
    float xs = (float)(w - 1 + k % 3) + dx;
    float y0f = floorf(ys), x0f = floorf(xs);
    float ty = ys - y0f, tx = xs - x0f;
    int yi = (int)y0f, xi = (int)x0f;
    float v = 0.f;
    if (yi >= 0     && yi < HH     && xi >= 0     && xi < WWD)
      v = fmaf(ysrc[yi * WWD + xi],           (1.f - ty) * (1.f - tx), v);
    if (yi >= 0     && yi < HH     && xi + 1 >= 0 && xi + 1 < WWD)
      v = fmaf(ysrc[yi * WWD + xi + 1],       (1.f - ty) * tx, v);
    if (yi + 1 >= 0 && yi + 1 < HH && xi >= 0     && xi < WWD)
      v = fmaf(ysrc[(yi + 1) * WWD + xi],     ty * (1.f - tx), v);
    if (yi + 1 >= 0 && yi + 1 < HH && xi + 1 >= 0 && xi + 1 < WWD)
      v = fmaf(ysrc[(yi + 1) * WWD + xi + 1], ty * tx, v);
    sl[ci * KK + k] = v * mk;
  }
  __syncthreads();
  // phase 2: this thread is output channel `ci` of pixel `pix`
  float acc = b_dc[ci];
  const float* wrow = w_dc + ci * CCH * KK;
  #pragma unroll 8
  for (int m = 0; m < CCH * KK; m++)
    acc = fmaf(wrow[m], sl[m], acc);
  size_t o = ((size_t)b * CCH + ci) * HWv + hw;
  outp[o] = x0[o] + acc;
}

// ---------------- conv 3x3, 64->64. MODE 0: leaky out. MODE 1: +residual ----
template <int MODE>
__global__ __launch_bounds__(256) void conv3x3_k(const float* __restrict__ in,
    const float* __restrict__ wgt, const float* __restrict__ bias,
    const float* __restrict__ res, float* __restrict__ outp) {
  int idx = blockIdx.x * 256 + threadIdx.x;           // over B*C*HW
  int hw = idx & (HWv - 1);
  int co = (idx >> 14) & 63;
  int b  = idx >> 20;
  int h = hw >> 7, w = hw & 127;
  float acc = bias[co];
  const float* wb   = wgt + co * CCH * 9;
  const float* src0 = in + (size_t)b * CCH * HWv;
  for (int ci = 0; ci < CCH; ci++) {
    const float* src = src0 + ci * HWv;
    const float* wk  = wb + ci * 9;
    #pragma unroll
    for (int dy = 0; dy < 3; dy++) {
      int hh = h - 1 + dy;
      if ((unsigned)hh >= HH) continue;
      #pragma unroll
      for (int dx = 0; dx < 3; dx++) {
        int ww = w - 1 + dx;
        if ((unsigned)ww >= WWD) continue;
        acc = fmaf(wk[dy * 3 + dx], src[hh * WWD + ww], acc);
      }
    }
  }
  if (MODE == 0) {
    outp[idx] = acc >= 0.f ? acc : 0.2f * acc;
  } else {
    outp[idx] = acc + res[idx];
  }
}

extern "C" void kernel_launch(void* const* d_in, const int* in_sizes, int n_in,
                              void* d_out, int out_size, void* d_ws, size_t ws_size,
                              hipStream_t stream) {
  const float* x    = (const float*)d_in[0];
  const float* y    = (const float*)d_in[1];
  const float* w0   = (const float*)d_in[2];
  const float* b0   = (const float*)d_in[3];
  const float* w_om = (const float*)d_in[4];
  const float* b_om = (const float*)d_in[5];
  const float* w_dc = (const float*)d_in[6];
  const float* b_dc = (const float*)d_in[7];
  const float* w1   = (const float*)d_in[8];
  const float* b1   = (const float*)d_in[9];
  const float* w2   = (const float*)d_in[10];
  const float* b2   = (const float*)d_in[11];
  float* out = (float*)d_out;

  const size_t NFULL = (size_t)BB * CCH * HWv;        // 2,097,152
  const size_t NOM   = (size_t)BB * 27 * HWv;         //   884,736
  float* x0  = (float*)d_ws;
  float* om  = x0 + NFULL;
  float* ob  = om + NOM;                               // deform output ("out")
  float* z1  = ob + NFULL;

  // 1. conv1x1
  conv1x1_k<<<NFULL / 256, 256, 0, stream>>>(x, w0, b0, x0);
  // 2. offset/mask conv
  conv_om_k<<<(NOM + 255) / 256, 256, 0, stream>>>(x0, y, w_om, b_om, om);
  // 3. deformable conv + x0 residual
  deform_k<<<(BB * HWv) / 4, 256, 0, stream>>>(y, om, x0, w_dc, b_dc, ob);
  // 4. conv w1 + leaky relu
  conv3x3_k<0><<<NFULL / 256, 256, 0, stream>>>(ob, w1, b1, nullptr, z1);
  // 5. conv w2 + residual ob
  conv3x3_k<1><<<NFULL / 256, 256, 0, stream>>>(z1, w2, b2, ob, out);
}

// Round 2
// 739.120 us; speedup vs baseline: 2.3654x; 2.3654x over previous
//
#include <hip/hip_runtime.h>
#include <hip/hip_bf16.h>
#include <math.h>

#define BB 2
#define CCH 64
#define HH 128
#define WWD 128
#define HWv (HH*WWD)
#define KK 9
#define PPB 16          // pixels per block (contiguous along w)
#define KTOT (CCH*KK)   // 576
#define KSTEP 18        // 576 / 32
#define SROW 584        // samp row stride in bf16 (576 + 8 pad -> 2-way bank alias, free)

typedef __attribute__((ext_vector_type(8))) short bf16x8;
typedef __attribute__((ext_vector_type(4))) float f32x4;

__device__ inline unsigned short f2bf(float f) {
  __hip_bfloat16 h = __float2bfloat16(f);
  return *reinterpret_cast<unsigned short*>(&h);
}

// ---------------- conv 1x1 : x0 = w0 @ x + b0 (unchanged) ----------------
__global__ __launch_bounds__(256) void conv1x1_k(const float* __restrict__ x,
    const float* __restrict__ w0, const float* __restrict__ b0,
    float* __restrict__ x0) {
  int idx = blockIdx.x * 256 + threadIdx.x;
  int hw = idx & (HWv - 1);
  int co = (idx >> 14) & 63;
  int b  = idx >> 20;
  const float* xin  = x + (size_t)b * CCH * HWv + hw;
  const float* wrow = w0 + co * CCH;
  float acc = b0[co];
  #pragma unroll
  for (int ci = 0; ci < CCH; ci++)
    acc = fmaf(wrow[ci], xin[ci * HWv], acc);
  x0[idx] = acc;
}

// ---------------- conv 3x3, 128ch in (concat x0,y), 27ch out (unchanged) ----
__global__ __launch_bounds__(256) void conv_om_k(const float* __restrict__ x0,
    const float* __restrict__ y, const float* __restrict__ w_om,
    const float* __restrict__ b_om, float* __restrict__ om) {
  int idx = blockIdx.x * 256 + threadIdx.x;
  if (idx >= BB * 27 * HWv) return;
  int hw = idx & (HWv - 1);
  int co = (idx >> 14) % 27;
  int b  = idx / (27 * HWv);
  int h = hw >> 7, w = hw & 127;
  float acc = b_om[co];
  const float* wb = w_om + co * 128 * 9;
  for (int ci = 0; ci < 128; ci++) {
    const float* src = (ci < CCH) ? (x0 + ((size_t)b * CCH + ci) * HWv)
                                  : (y  + ((size_t)b * CCH + (ci - CCH)) * HWv);
    const float* wk = wb + ci * 9;
    #pragma unroll
    for (int dy = 0; dy < 3; dy++) {
      int hh = h - 1 + dy;
      if ((unsigned)hh >= HH) continue;
      #pragma unroll
      for (int dx = 0; dx < 3; dx++) {
        int ww = w - 1 + dx;
        if ((unsigned)ww >= WWD) continue;
        acc = fmaf(wk[dy * 3 + dx], src[hh * WWD + ww], acc);
      }
    }
  }
  om[idx] = acc;
}

// ---------------- weight pack: w[64 co][576 k] -> frag order --------------
// pack scalar idx = ((q*18+s)*64 + lane)*8 + j  holds  w[co=q*16+(lane&15)]
//                                                      [k = s*32+(lane>>4)*8+j]
__global__ __launch_bounds__(256) void pack_w_k(const float* __restrict__ w,
    unsigned short* __restrict__ pack) {
  int idx = blockIdx.x * 256 + threadIdx.x;   // 4*18*64*8 = 36864
  int j = idx & 7;
  int l = (idx >> 3) & 63;
  int s = (idx >> 9) % KSTEP;
  int q = idx / (KSTEP * 512);
  int co = q * 16 + (l & 15);
  int k  = s * 32 + (l >> 4) * 8 + j;
  pack[idx] = f2bf(w[co * KTOT + k]);
}

// ---------------- unified MFMA conv over K=576 ----------------------------
// MODE 0: deform (in=y, offsets/mask from om, +res(x0))
// MODE 1: conv3x3 + leaky            (in=ob)
// MODE 2: conv3x3 + residual res(ob) (in=z1)
// Block: 256 thr = 4 waves; 16 pixels (one strip along w); wave q = co quadrant.
template <int MODE>
__global__ __launch_bounds__(256) void mconv_k(const float* __restrict__ in,
    const float* __restrict__ om, const float* __restrict__ res,
    const unsigned short* __restrict__ wpack, const float* __restrict__ bias,
    float* __restrict__ outp) {
  __shared__ __align__(16) unsigned short samp[PPB * SROW];

  int tid = threadIdx.x;
  int pixbase = blockIdx.x * PPB;           // over B*HW
  int hwb = pixbase & (HWv - 1);
  int b   = pixbase >> 14;
  int h   = hwb >> 7;
  int wb  = hwb & 127;

  if (MODE == 0) {
    __shared__ float prm[6][PPB * KK];
    if (tid < PPB * KK) {
      int pix = tid / KK, k = tid % KK;
      int hw = hwb + pix;
      const float* omb = om + (size_t)b * 27 * HWv + hw;
      float dy = omb[(2 * k) * HWv];
      float dx = omb[(2 * k + 1) * HWv];
      float mk = 2.f / (1.f + expf(-omb[(18 + k) * HWv]));
      float ys = (float)(h - 1 + k / 3) + dy;
      float xs = (float)(wb + pix - 1 + k % 3) + dx;
      float y0f = floorf(ys), x0f = floorf(xs);
      float ty = ys - y0f, tx = xs - x0f;
      prm[0][tid] = y0f;
      prm[1][tid] = x0f;
      prm[2][tid] = (1.f - ty) * (1.f - tx) * mk;
      prm[3][tid] = (1.f - ty) * tx * mk;
      prm[4][tid] = ty * (1.f - tx) * mk;
      prm[5][tid] = ty * tx * mk;
    }
    __syncthreads();
    int ci = tid & 63, pg = tid >> 6;
    const float* ysrc = in + ((size_t)b * CCH + ci) * HWv;
    for (int p4 = 0; p4 < 4; p4++) {
      int pix = pg * 4 + p4;
      #pragma unroll
      for (int k = 0; k < KK; k++) {
        int e = pix * KK + k;
        int yi = (int)prm[0][e], xi = (int)prm[1][e];
        bool y0v = (yi >= 0) & (yi < HH);
        bool y1v = (yi + 1 >= 0) & (yi + 1 < HH);
        bool x0v = (xi >= 0) & (xi < WWD);
        bool x1v = (xi + 1 >= 0) & (xi + 1 < WWD);
        float v = 0.f;
        if (y0v && x0v) v = fmaf(ysrc[yi * WWD + xi],           prm[2][e], v);
        if (y0v && x1v) v = fmaf(ysrc[yi * WWD + xi + 1],       prm[3][e], v);
        if (y1v && x0v) v = fmaf(ysrc[(yi + 1) * WWD + xi],     prm[4][e], v);
        if (y1v && x1v) v = fmaf(ysrc[(yi + 1) * WWD + xi + 1], prm[5][e], v);
        samp[pix * SROW + ci * KK + k] = f2bf(v);
      }
    }
  } else {
    int ci = tid & 63, pg = tid >> 6;
    const float* src = in + ((size_t)b * CCH + ci) * HWv;
    float rowv[3][6];
    #pragma unroll
    for (int r = 0; r < 3; r++) {
      int hh = h - 1 + r;
      #pragma unroll
      for (int c = 0; c < 6; c++) {
        int ww = wb + pg * 4 - 1 + c;
        rowv[r][c] = ((unsigned)hh < HH && (unsigned)ww < WWD)
                         ? src[hh * WWD + ww] : 0.f;
      }
    }
    #pragma unroll
    for (int p4 = 0; p4 < 4; p4++) {
      int pix = pg * 4 + p4;
      #pragma unroll
      for (int k = 0; k < KK; k++)
        samp[pix * SROW + ci * KK + k] = f2bf(rowv[k / 3][p4 + k % 3]);
    }
  }
  __syncthreads();

  // ---- MFMA: out[16 pix][16 co-quadrant] ----
  int lane = tid & 63;
  int q = tid >> 6;
  f32x4 acc = {0.f, 0.f, 0.f, 0.f};
  int rowA = lane & 15;          // pixel
  int g = lane >> 4;             // k-subgroup
  const unsigned short* arow = samp + rowA * SROW + g * 8;
  const bf16x8* bp = (const bf16x8*)wpack + (size_t)(q * KSTEP) * 64 + lane;
  #pragma unroll
  for (int s = 0; s < KSTEP; s++) {
    bf16x8 a = *(const bf16x8*)(arow + s * 32);
    bf16x8 bf = bp[(size_t)s * 64];
    acc = __builtin_amdgcn_mfma_f32_16x16x32_bf16(a, bf, acc, 0, 0, 0);
  }

  // D: col = lane&15 (co in quadrant), row = (lane>>4)*4 + reg (pixel)
  int co = q * 16 + (lane & 15);
  int pixr = (lane >> 4) * 4;
  size_t obase = ((size_t)b * CCH + co) * HWv + hwb + pixr;
  float bv = bias[co];
  float4 r;
  if (MODE == 0 || MODE == 2) {
    const float4 rv = *(const float4*)(res + obase);
    r.x = acc[0] + bv + rv.x;
    r.y = acc[1] + bv + rv.y;
    r.z = acc[2] + bv + rv.z;
    r.w = acc[3] + bv + rv.w;
  } else {
    float v0 = acc[0] + bv, v1 = acc[1] + bv, v2 = acc[2] + bv, v3 = acc[3] + bv;
    r.x = v0 >= 0.f ? v0 : 0.2f * v0;
    r.y = v1 >= 0.f ? v1 : 0.2f * v1;
    r.z = v2 >= 0.f ? v2 : 0.2f * v2;
    r.w = v3 >= 0.f ? v3 : 0.2f * v3;
  }
  *(float4*)(outp + obase) = r;
}

extern "C" void kernel_launch(void* const* d_in, const int* in_sizes, int n_in,
                              void* d_out, int out_size, void* d_ws, size_t ws_size,
                              hipStream_t stream) {
  const float* x    = (const float*)d_in[0];
  const float* y    = (const float*)d_in[1];
  const float* w0   = (const float*)d_in[2];
  const float* b0   = (const float*)d_in[3];
  const float* w_om = (const float*)d_in[4];
  const float* b_om = (const float*)d_in[5];
  const float* w_dc = (const float*)d_in[6];
  const float* b_dc = (const float*)d_in[7];
  const float* w1   = (const float*)d_in[8];
  const float* b1   = (const float*)d_in[9];
  const float* w2   = (const float*)d_in[10];
  const float* b2   = (const float*)d_in[11];
  float* out = (float*)d_out;

  const size_t NFULL = (size_t)BB * CCH * HWv;   // 2,097,152
  const size_t NOM   = (size_t)BB * 27 * HWv;    //   884,736
  const size_t NPACK = 4 * KSTEP * 64 * 8;       //    36,864 (bf16 elems)
  float* x0 = (float*)d_ws;
  float* om = x0 + NFULL;
  float* ob = om + NOM;
  float* z1 = ob + NFULL;
  unsigned short* pk_dc = (unsigned short*)(z1 + NFULL);
  unsigned short* pk_w1 = pk_dc + NPACK;
  unsigned short* pk_w2 = pk_w1 + NPACK;

  const int packBlocks = (int)(NPACK / 256);     // 144
  pack_w_k<<<packBlocks, 256, 0, stream>>>(w_dc, pk_dc);
  pack_w_k<<<packBlocks, 256, 0, stream>>>(w1, pk_w1);
  pack_w_k<<<packBlocks, 256, 0, stream>>>(w2, pk_w2);

  // 1. conv1x1
  conv1x1_k<<<NFULL / 256, 256, 0, stream>>>(x, w0, b0, x0);
  // 2. offset/mask conv
  conv_om_k<<<(NOM + 255) / 256, 256, 0, stream>>>(x0, y, w_om, b_om, om);

  const int mblocks = (int)((size_t)BB * HWv / PPB);  // 2048
  // 3. deformable conv + x0 residual
  mconv_k<0><<<mblocks, 256, 0, stream>>>(y, om, x0, pk_dc, b_dc, ob);
  // 4. conv w1 + leaky relu
  mconv_k<1><<<mblocks, 256, 0, stream>>>(ob, nullptr, nullptr, pk_w1, b1, z1);
  // 5. conv w2 + residual ob
  mconv_k<2><<<mblocks, 256, 0, stream>>>(z1, nullptr, ob, pk_w2, b2, out);
}

// Round 3
// 439.606 us; speedup vs baseline: 3.9769x; 1.6813x over previous
//
#include <hip/hip_runtime.h>
#include <hip/hip_bf16.h>
#include <math.h>

#define BB 2
#define CCH 64
#define HH 128
#define WWD 128
#define HWv (HH*WWD)
#define KK 9
#define PPB 16          // pixels per block for mconv (strip along w)
#define KTOT (CCH*KK)   // 576
#define KSTEP 18        // 576 / 32
#define SROW 584        // mconv samp row stride in bf16

#define OMK 1152        // om conv K = 128*9
#define OMROW 1160      // om samp row stride (1152 + 8)
#define OMKS 36         // 1152/32

typedef __attribute__((ext_vector_type(8))) short bf16x8;
typedef __attribute__((ext_vector_type(4))) float f32x4;

__device__ inline unsigned short f2bf(float f) {
  __hip_bfloat16 h = __float2bfloat16(f);
  return *reinterpret_cast<unsigned short*>(&h);
}

// ================= weight packing to MFMA fragment order ==================
// generic: w[co][k], co padded to NQ*16 (zeros), k padded to NS*32
// pack[((q*NS+s)*64 + lane)*8 + j] = w[q*16+(lane&15)][s*32+(lane>>4)*8+j]
template <int NQ, int NS, int NCO, int NK>
__global__ __launch_bounds__(256) void pack_k(const float* __restrict__ w,
    unsigned short* __restrict__ pack) {
  int idx = blockIdx.x * 256 + threadIdx.x;   // NQ*NS*512
  if (idx >= NQ * NS * 512) return;
  int j = idx & 7;
  int l = (idx >> 3) & 63;
  int s = (idx >> 9) % NS;
  int q = idx / (NS * 512);
  int co = q * 16 + (l & 15);
  int k  = s * 32 + (l >> 4) * 8 + j;
  pack[idx] = (co < NCO && k < NK) ? f2bf(w[co * NK + k]) : (unsigned short)0;
}

// ================= conv1x1 via MFMA: 64 px x 64 co, K=64 ==================
__global__ __launch_bounds__(256) void conv1x1_mfma_k(const float* __restrict__ x,
    const unsigned short* __restrict__ wpack, const float* __restrict__ b0,
    float* __restrict__ x0) {
  #define S1ROW 72
  __shared__ __align__(16) unsigned short samp1[64 * S1ROW];  // 9216 B
  int tid = threadIdx.x;
  int lane = tid & 63, q = tid >> 6;
  int pixbase = blockIdx.x * 64;
  int hwb = pixbase & (HWv - 1);
  int b = pixbase >> 14;
  // stage: lane = pixel (coalesced), each thread 16 ci values
  {
    unsigned short tmp[16];
    #pragma unroll
    for (int i = 0; i < 16; i++) {
      int ci = q * 16 + i;
      tmp[i] = f2bf(x[((size_t)b * CCH + ci) * HWv + hwb + lane]);
    }
    #pragma unroll
    for (int i = 0; i < 2; i++)
      *(bf16x8*)(samp1 + lane * S1ROW + q * 16 + i * 8) = *(bf16x8*)(tmp + i * 8);
  }
  __syncthreads();
  f32x4 acc[4] = {{0,0,0,0},{0,0,0,0},{0,0,0,0},{0,0,0,0}};
  int g = lane >> 4;
  const bf16x8* bp = (const bf16x8*)wpack + (size_t)(q * 2) * 64 + lane;
  #pragma unroll
  for (int s = 0; s < 2; s++) {
    bf16x8 bf = bp[(size_t)s * 64];
    #pragma unroll
    for (int t = 0; t < 4; t++) {
      bf16x8 a = *(const bf16x8*)(samp1 + (t * 16 + (lane & 15)) * S1ROW + g * 8 + s * 32);
      acc[t] = __builtin_amdgcn_mfma_f32_16x16x32_bf16(a, bf, acc[t], 0, 0, 0);
    }
  }
  int co = q * 16 + (lane & 15);
  float bv = b0[co];
  size_t obase = ((size_t)b * CCH + co) * HWv + hwb + g * 4;
  #pragma unroll
  for (int t = 0; t < 4; t++) {
    float4 r = {acc[t][0] + bv, acc[t][1] + bv, acc[t][2] + bv, acc[t][3] + bv};
    *(float4*)(x0 + obase + t * 16) = r;
  }
}

// ========== om conv via MFMA: 16 px x 32 co(27), K=1152, K-split ==========
__global__ __launch_bounds__(256) void om_mfma_k(const float* __restrict__ x0,
    const float* __restrict__ y, const unsigned short* __restrict__ wpack,
    const float* __restrict__ bias, float* __restrict__ om) {
  __shared__ __align__(16) unsigned short samp[PPB * OMROW];  // 37,120 B
  __shared__ __align__(16) float red[2 * 64 * 4];             // 2 KB
  int tid = threadIdx.x;
  int pixbase = blockIdx.x * PPB;
  int hwb = pixbase & (HWv - 1);
  int b = pixbase >> 14;
  int h = hwb >> 7, wb = hwb & 127;

  // stage im2col: thread = (ci 0..127, pg 0..1), 8 pixels each
  {
    int ci = tid & 127, pg = tid >> 7;
    const float* src = (ci < CCH) ? (x0 + ((size_t)b * CCH + ci) * HWv)
                                  : (y  + ((size_t)b * CCH + (ci - CCH)) * HWv);
    float rowv[3][10];
    #pragma unroll
    for (int r = 0; r < 3; r++) {
      int hh = h - 1 + r;
      #pragma unroll
      for (int c = 0; c < 10; c++) {
        int ww = wb + pg * 8 - 1 + c;
        rowv[r][c] = ((unsigned)hh < HH && (unsigned)ww < WWD)
                         ? src[hh * WWD + ww] : 0.f;
      }
    }
    #pragma unroll
    for (int p = 0; p < 8; p++) {
      int pix = pg * 8 + p;
      #pragma unroll
      for (int k = 0; k < KK; k++)
        samp[pix * OMROW + ci * KK + k] = f2bf(rowv[k / 3][p + k % 3]);
    }
  }
  __syncthreads();

  int lane = tid & 63, q = tid >> 6;
  int cohalf = q & 1, khalf = q >> 1;
  f32x4 acc = {0.f, 0.f, 0.f, 0.f};
  const unsigned short* arow = samp + (lane & 15) * OMROW + khalf * 576 + (lane >> 4) * 8;
  const bf16x8* bp = (const bf16x8*)wpack + (size_t)((cohalf * OMKS + khalf * 18)) * 64 + lane;
  #pragma unroll
  for (int s = 0; s < 18; s++) {
    bf16x8 a = *(const bf16x8*)(arow + s * 32);
    bf16x8 bf = bp[(size_t)s * 64];
    acc = __builtin_amdgcn_mfma_f32_16x16x32_bf16(a, bf, acc, 0, 0, 0);
  }
  if (khalf) {
    *(f32x4*)(red + (cohalf * 64 + lane) * 4) = acc;
  }
  __syncthreads();
  if (!khalf) {
    f32x4 o = *(const f32x4*)(red + (cohalf * 64 + lane) * 4);
    int co = cohalf * 16 + (lane & 15);
    if (co < 27) {
      float bv = bias[co];
      int pixr = (lane >> 4) * 4;
      float4 r = {acc[0] + o[0] + bv, acc[1] + o[1] + bv,
                  acc[2] + o[2] + bv, acc[3] + o[3] + bv};
      *(float4*)(om + ((size_t)b * 27 + co) * HWv + hwb + pixr) = r;
    }
  }
}

// ---------------- unified MFMA conv over K=576 (unchanged) ----------------
// MODE 0: deform (in=y, offsets/mask from om, +res(x0))
// MODE 1: conv3x3 + leaky            (in=ob)
// MODE 2: conv3x3 + residual res(ob) (in=z1)
template <int MODE>
__global__ __launch_bounds__(256) void mconv_k(const float* __restrict__ in,
    const float* __restrict__ om, const float* __restrict__ res,
    const unsigned short* __restrict__ wpack, const float* __restrict__ bias,
    float* __restrict__ outp) {
  __shared__ __align__(16) unsigned short samp[PPB * SROW];

  int tid = threadIdx.x;
  int pixbase = blockIdx.x * PPB;           // over B*HW
  int hwb = pixbase & (HWv - 1);
  int b   = pixbase >> 14;
  int h   = hwb >> 7;
  int wb  = hwb & 127;

  if (MODE == 0) {
    __shared__ float prm[6][PPB * KK];
    if (tid < PPB * KK) {
      int pix = tid / KK, k = tid % KK;
      int hw = hwb + pix;
      const float* omb = om + (size_t)b * 27 * HWv + hw;
      float dy = omb[(2 * k) * HWv];
      float dx = omb[(2 * k + 1) * HWv];
      float mk = 2.f / (1.f + expf(-omb[(18 + k) * HWv]));
      float ys = (float)(h - 1 + k / 3) + dy;
      float xs = (float)(wb + pix - 1 + k % 3) + dx;
      float y0f = floorf(ys), x0f = floorf(xs);
      float ty = ys - y0f, tx = xs - x0f;
      prm[0][tid] = y0f;
      prm[1][tid] = x0f;
      prm[2][tid] = (1.f - ty) * (1.f - tx) * mk;
      prm[3][tid] = (1.f - ty) * tx * mk;
      prm[4][tid] = ty * (1.f - tx) * mk;
      prm[5][tid] = ty * tx * mk;
    }
    __syncthreads();
    int ci = tid & 63, pg = tid >> 6;
    const float* ysrc = in + ((size_t)b * CCH + ci) * HWv;
    for (int p4 = 0; p4 < 4; p4++) {
      int pix = pg * 4 + p4;
      #pragma unroll
      for (int k = 0; k < KK; k++) {
        int e = pix * KK + k;
        int yi = (int)prm[0][e], xi = (int)prm[1][e];
        bool y0v = (yi >= 0) & (yi < HH);
        bool y1v = (yi + 1 >= 0) & (yi + 1 < HH);
        bool x0v = (xi >= 0) & (xi < WWD);
        bool x1v = (xi + 1 >= 0) & (xi + 1 < WWD);
        float v = 0.f;
        if (y0v && x0v) v = fmaf(ysrc[yi * WWD + xi],           prm[2][e], v);
        if (y0v && x1v) v = fmaf(ysrc[yi * WWD + xi + 1],       prm[3][e], v);
        if (y1v && x0v) v = fmaf(ysrc[(yi + 1) * WWD + xi],     prm[4][e], v);
        if (y1v && x1v) v = fmaf(ysrc[(yi + 1) * WWD + xi + 1], prm[5][e], v);
        samp[pix * SROW + ci * KK + k] = f2bf(v);
      }
    }
  } else {
    int ci = tid & 63, pg = tid >> 6;
    const float* src = in + ((size_t)b * CCH + ci) * HWv;
    float rowv[3][6];
    #pragma unroll
    for (int r = 0; r < 3; r++) {
      int hh = h - 1 + r;
      #pragma unroll
      for (int c = 0; c < 6; c++) {
        int ww = wb + pg * 4 - 1 + c;
        rowv[r][c] = ((unsigned)hh < HH && (unsigned)ww < WWD)
                         ? src[hh * WWD + ww] : 0.f;
      }
    }
    #pragma unroll
    for (int p4 = 0; p4 < 4; p4++) {
      int pix = pg * 4 + p4;
      #pragma unroll
      for (int k = 0; k < KK; k++)
        samp[pix * SROW + ci * KK + k] = f2bf(rowv[k / 3][p4 + k % 3]);
    }
  }
  __syncthreads();

  // ---- MFMA: out[16 pix][16 co-quadrant] ----
  int lane = tid & 63;
  int q = tid >> 6;
  f32x4 acc = {0.f, 0.f, 0.f, 0.f};
  int rowA = lane & 15;          // pixel
  int g = lane >> 4;             // k-subgroup
  const unsigned short* arow = samp + rowA * SROW + g * 8;
  const bf16x8* bp = (const bf16x8*)wpack + (size_t)(q * KSTEP) * 64 + lane;
  #pragma unroll
  for (int s = 0; s < KSTEP; s++) {
    bf16x8 a = *(const bf16x8*)(arow + s * 32);
    bf16x8 bf = bp[(size_t)s * 64];
    acc = __builtin_amdgcn_mfma_f32_16x16x32_bf16(a, bf, acc, 0, 0, 0);
  }

  // D: col = lane&15 (co in quadrant), row = (lane>>4)*4 + reg (pixel)
  int co = q * 16 + (lane & 15);
  int pixr = (lane >> 4) * 4;
  size_t obase = ((size_t)b * CCH + co) * HWv + hwb + pixr;
  float bv = bias[co];
  float4 r;
  if (MODE == 0 || MODE == 2) {
    const float4 rv = *(const float4*)(res + obase);
    r.x = acc[0] + bv + rv.x;
    r.y = acc[1] + bv + rv.y;
    r.z = acc[2] + bv + rv.z;
    r.w = acc[3] + bv + rv.w;
  } else {
    float v0 = acc[0] + bv, v1 = acc[1] + bv, v2 = acc[2] + bv, v3 = acc[3] + bv;
    r.x = v0 >= 0.f ? v0 : 0.2f * v0;
    r.y = v1 >= 0.f ? v1 : 0.2f * v1;
    r.z = v2 >= 0.f ? v2 : 0.2f * v2;
    r.w = v3 >= 0.f ? v3 : 0.2f * v3;
  }
  *(float4*)(outp + obase) = r;
}

extern "C" void kernel_launch(void* const* d_in, const int* in_sizes, int n_in,
                              void* d_out, int out_size, void* d_ws, size_t ws_size,
                              hipStream_t stream) {
  const float* x    = (const float*)d_in[0];
  const float* y    = (const float*)d_in[1];
  const float* w0   = (const float*)d_in[2];
  const float* b0   = (const float*)d_in[3];
  const float* w_om = (const float*)d_in[4];
  const float* b_om = (const float*)d_in[5];
  const float* w_dc = (const float*)d_in[6];
  const float* b_dc = (const float*)d_in[7];
  const float* w1   = (const float*)d_in[8];
  const float* b1   = (const float*)d_in[9];
  const float* w2   = (const float*)d_in[10];
  const float* b2   = (const float*)d_in[11];
  float* out = (float*)d_out;

  const size_t NFULL = (size_t)BB * CCH * HWv;   // 2,097,152
  const size_t NOM   = (size_t)BB * 27 * HWv;    //   884,736
  const size_t NPACK = 4 * KSTEP * 64 * 8;       //    36,864 (bf16 elems)
  const size_t NPACKOM = 2 * OMKS * 64 * 8;      //    36,864
  const size_t NPACK1  = 4 * 2 * 64 * 8;         //     4,096
  float* x0 = (float*)d_ws;
  float* om = x0 + NFULL;
  float* ob = om + NOM;
  float* z1 = ob + NFULL;
  unsigned short* pk_dc = (unsigned short*)(z1 + NFULL);
  unsigned short* pk_w1 = pk_dc + NPACK;
  unsigned short* pk_w2 = pk_w1 + NPACK;
  unsigned short* pk_om = pk_w2 + NPACK;
  unsigned short* pk_0  = pk_om + NPACKOM;

  pack_k<4, KSTEP, 64, KTOT><<<(int)(NPACK / 256), 256, 0, stream>>>(w_dc, pk_dc);
  pack_k<4, KSTEP, 64, KTOT><<<(int)(NPACK / 256), 256, 0, stream>>>(w1, pk_w1);
  pack_k<4, KSTEP, 64, KTOT><<<(int)(NPACK / 256), 256, 0, stream>>>(w2, pk_w2);
  pack_k<2, OMKS, 27, OMK><<<(int)(NPACKOM / 256), 256, 0, stream>>>(w_om, pk_om);
  pack_k<4, 2, 64, 64><<<(int)(NPACK1 / 256), 256, 0, stream>>>(w0, pk_0);

  // 1. conv1x1 (MFMA)
  conv1x1_mfma_k<<<(int)((size_t)BB * HWv / 64), 256, 0, stream>>>(x, pk_0, b0, x0);
  // 2. offset/mask conv (MFMA, K-split)
  om_mfma_k<<<(int)((size_t)BB * HWv / PPB), 256, 0, stream>>>(x0, y, pk_om, b_om, om);

  const int mblocks = (int)((size_t)BB * HWv / PPB);  // 2048
  // 3. deformable conv + x0 residual
  mconv_k<0><<<mblocks, 256, 0, stream>>>(y, om, x0, pk_dc, b_dc, ob);
  // 4. conv w1 + leaky relu
  mconv_k<1><<<mblocks, 256, 0, stream>>>(ob, nullptr, nullptr, pk_w1, b1, z1);
  // 5. conv w2 + residual ob
  mconv_k<2><<<mblocks, 256, 0, stream>>>(z1, nullptr, ob, pk_w2, b2, out);
}

// Round 4
// 198.563 us; speedup vs baseline: 8.8047x; 2.2139x over previous
//
#include <hip/hip_runtime.h>
#include <hip/hip_bf16.h>
#include <math.h>

#define BB 2
#define CCH 64
#define HH 128
#define WWD 128
#define HWv (HH*WWD)
#define KK 9
#define PPB 16          // pixels per block for mconv (strip along w)
#define KTOT (CCH*KK)   // 576
#define KSTEP 18        // 576 / 32
#define SROW 584        // mconv samp row stride in bf16

#define OMK 1152        // om conv K = 128*9
#define OMROW 1160      // om samp row stride (1152 + 8)
#define OMKS 36         // 1152/32

typedef __attribute__((ext_vector_type(8))) short bf16x8;
typedef __attribute__((ext_vector_type(4))) float f32x4;

__device__ inline unsigned short f2bf(float f) {
  __hip_bfloat16 h = __float2bfloat16(f);
  return *reinterpret_cast<unsigned short*>(&h);
}

// ============ y NCHW -> NHWC transpose: yt[b][hw][ci] = y[b][ci][hw] =======
__global__ __launch_bounds__(256) void transpose_yk(const float* __restrict__ y,
    float* __restrict__ yt) {
  __shared__ float tile[64][65];
  int blk = blockIdx.x;                 // over B*HW/64 = 512
  int hwb = (blk * 64) & (HWv - 1);
  int b   = (blk * 64) >> 14;
  int tx = threadIdx.x & 63;
  int ty = threadIdx.x >> 6;            // 0..3
  const float* src = y + (size_t)b * CCH * HWv;
  #pragma unroll
  for (int i = 0; i < 16; i++) {
    int ci = i * 4 + ty;
    tile[ci][tx] = src[(size_t)ci * HWv + hwb + tx];
  }
  __syncthreads();
  float* dst = yt + ((size_t)b * HWv + hwb) * 64;
  #pragma unroll
  for (int i = 0; i < 16; i++) {
    int row = i * 4 + ty;
    dst[(size_t)row * 64 + tx] = tile[tx][row];
  }
}

// ================= weight packing to MFMA fragment order ==================
template <int NQ, int NS, int NCO, int NK>
__global__ __launch_bounds__(256) void pack_k(const float* __restrict__ w,
    unsigned short* __restrict__ pack) {
  int idx = blockIdx.x * 256 + threadIdx.x;   // NQ*NS*512
  if (idx >= NQ * NS * 512) return;
  int j = idx & 7;
  int l = (idx >> 3) & 63;
  int s = (idx >> 9) % NS;
  int q = idx / (NS * 512);
  int co = q * 16 + (l & 15);
  int k  = s * 32 + (l >> 4) * 8 + j;
  pack[idx] = (co < NCO && k < NK) ? f2bf(w[co * NK + k]) : (unsigned short)0;
}

// ================= conv1x1 via MFMA: 64 px x 64 co, K=64 ==================
__global__ __launch_bounds__(256) void conv1x1_mfma_k(const float* __restrict__ x,
    const unsigned short* __restrict__ wpack, const float* __restrict__ b0,
    float* __restrict__ x0) {
  #define S1ROW 72
  __shared__ __align__(16) unsigned short samp1[64 * S1ROW];  // 9216 B
  int tid = threadIdx.x;
  int lane = tid & 63, q = tid >> 6;
  int pixbase = blockIdx.x * 64;
  int hwb = pixbase & (HWv - 1);
  int b = pixbase >> 14;
  {
    unsigned short tmp[16];
    #pragma unroll
    for (int i = 0; i < 16; i++) {
      int ci = q * 16 + i;
      tmp[i] = f2bf(x[((size_t)b * CCH + ci) * HWv + hwb + lane]);
    }
    #pragma unroll
    for (int i = 0; i < 2; i++)
      *(bf16x8*)(samp1 + lane * S1ROW + q * 16 + i * 8) = *(bf16x8*)(tmp + i * 8);
  }
  __syncthreads();
  f32x4 acc[4] = {{0,0,0,0},{0,0,0,0},{0,0,0,0},{0,0,0,0}};
  int g = lane >> 4;
  const bf16x8* bp = (const bf16x8*)wpack + (size_t)(q * 2) * 64 + lane;
  #pragma unroll
  for (int s = 0; s < 2; s++) {
    bf16x8 bf = bp[(size_t)s * 64];
    #pragma unroll
    for (int t = 0; t < 4; t++) {
      bf16x8 a = *(const bf16x8*)(samp1 + (t * 16 + (lane & 15)) * S1ROW + g * 8 + s * 32);
      acc[t] = __builtin_amdgcn_mfma_f32_16x16x32_bf16(a, bf, acc[t], 0, 0, 0);
    }
  }
  int co = q * 16 + (lane & 15);
  float bv = b0[co];
  size_t obase = ((size_t)b * CCH + co) * HWv + hwb + g * 4;
  #pragma unroll
  for (int t = 0; t < 4; t++) {
    float4 r = {acc[t][0] + bv, acc[t][1] + bv, acc[t][2] + bv, acc[t][3] + bv};
    *(float4*)(x0 + obase + t * 16) = r;
  }
}

// ========== om conv via MFMA: 16 px x 32 co(27), K=1152, K-split ==========
__global__ __launch_bounds__(256) void om_mfma_k(const float* __restrict__ x0,
    const float* __restrict__ y, const unsigned short* __restrict__ wpack,
    const float* __restrict__ bias, float* __restrict__ om) {
  __shared__ __align__(16) unsigned short samp[PPB * OMROW];  // 37,120 B
  __shared__ __align__(16) float red[2 * 64 * 4];             // 2 KB
  int tid = threadIdx.x;
  int pixbase = blockIdx.x * PPB;
  int hwb = pixbase & (HWv - 1);
  int b = pixbase >> 14;
  int h = hwb >> 7, wb = hwb & 127;

  {
    int ci = tid & 127, pg = tid >> 7;
    const float* src = (ci < CCH) ? (x0 + ((size_t)b * CCH + ci) * HWv)
                                  : (y  + ((size_t)b * CCH + (ci - CCH)) * HWv);
    float rowv[3][10];
    #pragma unroll
    for (int r = 0; r < 3; r++) {
      int hh = h - 1 + r;
      #pragma unroll
      for (int c = 0; c < 10; c++) {
        int ww = wb + pg * 8 - 1 + c;
        rowv[r][c] = ((unsigned)hh < HH && (unsigned)ww < WWD)
                         ? src[hh * WWD + ww] : 0.f;
      }
    }
    #pragma unroll
    for (int p = 0; p < 8; p++) {
      int pix = pg * 8 + p;
      #pragma unroll
      for (int k = 0; k < KK; k++)
        samp[pix * OMROW + ci * KK + k] = f2bf(rowv[k / 3][p + k % 3]);
    }
  }
  __syncthreads();

  int lane = tid & 63, q = tid >> 6;
  int cohalf = q & 1, khalf = q >> 1;
  f32x4 acc = {0.f, 0.f, 0.f, 0.f};
  const unsigned short* arow = samp + (lane & 15) * OMROW + khalf * 576 + (lane >> 4) * 8;
  const bf16x8* bp = (const bf16x8*)wpack + (size_t)((cohalf * OMKS + khalf * 18)) * 64 + lane;
  #pragma unroll
  for (int s = 0; s < 18; s++) {
    bf16x8 a = *(const bf16x8*)(arow + s * 32);
    bf16x8 bf = bp[(size_t)s * 64];
    acc = __builtin_amdgcn_mfma_f32_16x16x32_bf16(a, bf, acc, 0, 0, 0);
  }
  if (khalf) {
    *(f32x4*)(red + (cohalf * 64 + lane) * 4) = acc;
  }
  __syncthreads();
  if (!khalf) {
    f32x4 o = *(const f32x4*)(red + (cohalf * 64 + lane) * 4);
    int co = cohalf * 16 + (lane & 15);
    if (co < 27) {
      float bv = bias[co];
      int pixr = (lane >> 4) * 4;
      float4 r = {acc[0] + o[0] + bv, acc[1] + o[1] + bv,
                  acc[2] + o[2] + bv, acc[3] + o[3] + bv};
      *(float4*)(om + ((size_t)b * 27 + co) * HWv + hwb + pixr) = r;
    }
  }
}

// ---------------- unified MFMA conv over K=576 ----------------------------
// MODE 0: deform (in = yt NHWC, offsets/mask from om, +res(x0))
// MODE 1: conv3x3 + leaky            (in=ob NCHW)
// MODE 2: conv3x3 + residual res(ob) (in=z1 NCHW)
template <int MODE>
__global__ __launch_bounds__(256) void mconv_k(const float* __restrict__ in,
    const float* __restrict__ om, const float* __restrict__ res,
    const unsigned short* __restrict__ wpack, const float* __restrict__ bias,
    float* __restrict__ outp) {
  __shared__ __align__(16) unsigned short samp[PPB * SROW];

  int tid = threadIdx.x;
  int pixbase = blockIdx.x * PPB;           // over B*HW
  int hwb = pixbase & (HWv - 1);
  int b   = pixbase >> 14;
  int h   = hwb >> 7;
  int wb  = hwb & 127;

  if (MODE == 0) {
    __shared__ float prm[6][PPB * KK];
    if (tid < PPB * KK) {
      int pix = tid / KK, k = tid % KK;
      int hw = hwb + pix;
      const float* omb = om + (size_t)b * 27 * HWv + hw;
      float dy = omb[(2 * k) * HWv];
      float dx = omb[(2 * k + 1) * HWv];
      float mk = 2.f / (1.f + expf(-omb[(18 + k) * HWv]));
      float ys = (float)(h - 1 + k / 3) + dy;
      float xs = (float)(wb + pix - 1 + k % 3) + dx;
      float y0f = floorf(ys), x0f = floorf(xs);
      float ty = ys - y0f, tx = xs - x0f;
      prm[0][tid] = y0f;
      prm[1][tid] = x0f;
      prm[2][tid] = (1.f - ty) * (1.f - tx) * mk;
      prm[3][tid] = (1.f - ty) * tx * mk;
      prm[4][tid] = ty * (1.f - tx) * mk;
      prm[5][tid] = ty * tx * mk;
    }
    __syncthreads();
    // coalesced gather from NHWC yt: wave-uniform (pix,k), lane = ci
    int lane = tid & 63, q = tid >> 6;
    const float* ytb = in + (size_t)b * HWv * 64 + lane;
    #pragma unroll
    for (int p4 = 0; p4 < 4; p4++) {
      int pix = q * 4 + p4;
      #pragma unroll
      for (int k = 0; k < KK; k++) {
        int e = pix * KK + k;
        int yi = (int)prm[0][e], xi = (int)prm[1][e];
        float w00 = prm[2][e], w01 = prm[3][e];
        float w10 = prm[4][e], w11 = prm[5][e];
        bool y0v = (unsigned)yi < HH, y1v = (unsigned)(yi + 1) < HH;
        bool x0v = (unsigned)xi < WWD, x1v = (unsigned)(xi + 1) < WWD;
        long base = (long)yi * WWD + xi;
        float v = 0.f;
        if (y0v && x0v) v = fmaf(ytb[base * 64],             w00, v);
        if (y0v && x1v) v = fmaf(ytb[(base + 1) * 64],       w01, v);
        if (y1v && x0v) v = fmaf(ytb[(base + WWD) * 64],     w10, v);
        if (y1v && x1v) v = fmaf(ytb[(base + WWD + 1) * 64], w11, v);
        samp[pix * SROW + lane * KK + k] = f2bf(v);
      }
    }
  } else {
    int ci = tid & 63, pg = tid >> 6;
    const float* src = in + ((size_t)b * CCH + ci) * HWv;
    float rowv[3][6];
    #pragma unroll
    for (int r = 0; r < 3; r++) {
      int hh = h - 1 + r;
      #pragma unroll
      for (int c = 0; c < 6; c++) {
        int ww = wb + pg * 4 - 1 + c;
        rowv[r][c] = ((unsigned)hh < HH && (unsigned)ww < WWD)
                         ? src[hh * WWD + ww] : 0.f;
      }
    }
    #pragma unroll
    for (int p4 = 0; p4 < 4; p4++) {
      int pix = pg * 4 + p4;
      #pragma unroll
      for (int k = 0; k < KK; k++)
        samp[pix * SROW + ci * KK + k] = f2bf(rowv[k / 3][p4 + k % 3]);
    }
  }
  __syncthreads();

  // ---- MFMA: out[16 pix][16 co-quadrant] ----
  int lane = tid & 63;
  int q = tid >> 6;
  f32x4 acc = {0.f, 0.f, 0.f, 0.f};
  int rowA = lane & 15;          // pixel
  int g = lane >> 4;             // k-subgroup
  const unsigned short* arow = samp + rowA * SROW + g * 8;
  const bf16x8* bp = (const bf16x8*)wpack + (size_t)(q * KSTEP) * 64 + lane;
  #pragma unroll
  for (int s = 0; s < KSTEP; s++) {
    bf16x8 a = *(const bf16x8*)(arow + s * 32);
    bf16x8 bf = bp[(size_t)s * 64];
    acc = __builtin_amdgcn_mfma_f32_16x16x32_bf16(a, bf, acc, 0, 0, 0);
  }

  int co = q * 16 + (lane & 15);
  int pixr = (lane >> 4) * 4;
  size_t obase = ((size_t)b * CCH + co) * HWv + hwb + pixr;
  float bv = bias[co];
  float4 r;
  if (MODE == 0 || MODE == 2) {
    const float4 rv = *(const float4*)(res + obase);
    r.x = acc[0] + bv + rv.x;
    r.y = acc[1] + bv + rv.y;
    r.z = acc[2] + bv + rv.z;
    r.w = acc[3] + bv + rv.w;
  } else {
    float v0 = acc[0] + bv, v1 = acc[1] + bv, v2 = acc[2] + bv, v3 = acc[3] + bv;
    r.x = v0 >= 0.f ? v0 : 0.2f * v0;
    r.y = v1 >= 0.f ? v1 : 0.2f * v1;
    r.z = v2 >= 0.f ? v2 : 0.2f * v2;
    r.w = v3 >= 0.f ? v3 : 0.2f * v3;
  }
  *(float4*)(outp + obase) = r;
}

extern "C" void kernel_launch(void* const* d_in, const int* in_sizes, int n_in,
                              void* d_out, int out_size, void* d_ws, size_t ws_size,
                              hipStream_t stream) {
  const float* x    = (const float*)d_in[0];
  const float* y    = (const float*)d_in[1];
  const float* w0   = (const float*)d_in[2];
  const float* b0   = (const float*)d_in[3];
  const float* w_om = (const float*)d_in[4];
  const float* b_om = (const float*)d_in[5];
  const float* w_dc = (const float*)d_in[6];
  const float* b_dc = (const float*)d_in[7];
  const float* w1   = (const float*)d_in[8];
  const float* b1   = (const float*)d_in[9];
  const float* w2   = (const float*)d_in[10];
  const float* b2   = (const float*)d_in[11];
  float* out = (float*)d_out;

  const size_t NFULL = (size_t)BB * CCH * HWv;   // 2,097,152
  const size_t NOM   = (size_t)BB * 27 * HWv;    //   884,736
  const size_t NPACK = 4 * KSTEP * 64 * 8;       //    36,864 (bf16 elems)
  const size_t NPACKOM = 2 * OMKS * 64 * 8;      //    36,864
  const size_t NPACK1  = 4 * 2 * 64 * 8;         //     4,096
  float* x0 = (float*)d_ws;
  float* om = x0 + NFULL;
  float* ob = om + NOM;
  float* z1 = ob + NFULL;
  float* yt = z1;                                // alias: yt dead before z1 written
  unsigned short* pk_dc = (unsigned short*)(z1 + NFULL);
  unsigned short* pk_w1 = pk_dc + NPACK;
  unsigned short* pk_w2 = pk_w1 + NPACK;
  unsigned short* pk_om = pk_w2 + NPACK;
  unsigned short* pk_0  = pk_om + NPACKOM;

  pack_k<4, KSTEP, 64, KTOT><<<(int)(NPACK / 256), 256, 0, stream>>>(w_dc, pk_dc);
  pack_k<4, KSTEP, 64, KTOT><<<(int)(NPACK / 256), 256, 0, stream>>>(w1, pk_w1);
  pack_k<4, KSTEP, 64, KTOT><<<(int)(NPACK / 256), 256, 0, stream>>>(w2, pk_w2);
  pack_k<2, OMKS, 27, OMK><<<(int)(NPACKOM / 256), 256, 0, stream>>>(w_om, pk_om);
  pack_k<4, 2, 64, 64><<<(int)(NPACK1 / 256), 256, 0, stream>>>(w0, pk_0);

  // 0. y -> NHWC (into z1's buffer; consumed by mconv<0> before z1 is written)
  transpose_yk<<<(int)((size_t)BB * HWv / 64), 256, 0, stream>>>(y, yt);
  // 1. conv1x1 (MFMA)
  conv1x1_mfma_k<<<(int)((size_t)BB * HWv / 64), 256, 0, stream>>>(x, pk_0, b0, x0);
  // 2. offset/mask conv (MFMA, K-split)
  om_mfma_k<<<(int)((size_t)BB * HWv / PPB), 256, 0, stream>>>(x0, y, pk_om, b_om, om);

  const int mblocks = (int)((size_t)BB * HWv / PPB);  // 2048
  // 3. deformable conv + x0 residual (coalesced NHWC gather)
  mconv_k<0><<<mblocks, 256, 0, stream>>>(yt, om, x0, pk_dc, b_dc, ob);
  // 4. conv w1 + leaky relu
  mconv_k<1><<<mblocks, 256, 0, stream>>>(ob, nullptr, nullptr, pk_w1, b1, z1);
  // 5. conv w2 + residual ob
  mconv_k<2><<<mblocks, 256, 0, stream>>>(z1, nullptr, ob, pk_w2, b2, out);
}

// Round 5
// 127.690 us; speedup vs baseline: 13.6917x; 1.5550x over previous
//
#include <hip/hip_runtime.h>
#include <hip/hip_bf16.h>
#include <math.h>

#define BB 2
#define CCH 64
#define HH 128
#define WWD 128
#define HWv (HH*WWD)
#define KK 9
#define PPB 16          // pixels per block (strip along w)
#define KTOT 576        // mconv K
#define KSTEP 18        // 576/32
#define SROW 584        // mconv samp row stride (bf16): 576 + 8
#define OMK 1152        // om K = 128*9
#define OMROW 1160      // om samp row stride: 1152 + 8
#define OMKS 36         // 1152/32
#define OMC 32          // om_t NHWC channel stride (27 used)

typedef __attribute__((ext_vector_type(8))) short bf16x8;
typedef __attribute__((ext_vector_type(4))) float f32x4;

__device__ inline unsigned short f2bf(float f) {
  __hip_bfloat16 h = __float2bfloat16(f);
  return *reinterpret_cast<unsigned short*>(&h);
}
__device__ inline unsigned int f2bf2(float lo, float hi) {
  return ((unsigned int)f2bf(hi) << 16) | (unsigned int)f2bf(lo);
}

// ============ y NCHW -> NHWC: yt[b][hw][ci] ================================
__global__ __launch_bounds__(256) void transpose_yk(const float* __restrict__ y,
    float* __restrict__ yt) {
  __shared__ float tile[64][65];
  int blk = blockIdx.x;                 // B*HW/64 = 512
  int hwb = (blk * 64) & (HWv - 1);
  int b   = (blk * 64) >> 14;
  int tx = threadIdx.x & 63;
  int ty = threadIdx.x >> 6;            // 0..3
  const float* src = y + (size_t)b * CCH * HWv;
  #pragma unroll
  for (int i = 0; i < 16; i++) {
    int ci = i * 4 + ty;
    tile[ci][tx] = src[(size_t)ci * HWv + hwb + tx];
  }
  __syncthreads();
  float* dst = yt + ((size_t)b * HWv + hwb) * 64;
  #pragma unroll
  for (int i = 0; i < 16; i++) {
    int row = i * 4 + ty;
    dst[(size_t)row * 64 + tx] = tile[tx][row];
  }
}

// ============ weight pack, ci-major (1x1 conv) =============================
template <int NQ, int NS, int NCO, int NK>
__global__ __launch_bounds__(256) void pack_k(const float* __restrict__ w,
    unsigned short* __restrict__ pack) {
  int idx = blockIdx.x * 256 + threadIdx.x;   // NQ*NS*512
  if (idx >= NQ * NS * 512) return;
  int j = idx & 7;
  int l = (idx >> 3) & 63;
  int s = (idx >> 9) % NS;
  int q = idx / (NS * 512);
  int co = q * 16 + (l & 15);
  int k  = s * 32 + (l >> 4) * 8 + j;
  pack[idx] = (co < NCO && k < NK) ? f2bf(w[co * NK + k]) : (unsigned short)0;
}

// ============ weight pack, tap-major: k' = kk*CIN + ci =====================
template <int NQ, int NS, int NCO, int CIN>
__global__ __launch_bounds__(256) void pack_tap_k(const float* __restrict__ w,
    unsigned short* __restrict__ pack) {
  int idx = blockIdx.x * 256 + threadIdx.x;   // NQ*NS*512
  if (idx >= NQ * NS * 512) return;
  int j = idx & 7;
  int l = (idx >> 3) & 63;
  int s = (idx >> 9) % NS;
  int q = idx / (NS * 512);
  int co = q * 16 + (l & 15);
  int kp = s * 32 + (l >> 4) * 8 + j;
  int ci = kp % CIN;
  int kk = kp / CIN;
  pack[idx] = (co < NCO && kk < KK)
                  ? f2bf(w[(co * CIN + ci) * KK + kk]) : (unsigned short)0;
}

// ============ conv1x1 via MFMA: 64 px x 64 co, K=64, OUT = NHWC x0t ========
__global__ __launch_bounds__(256) void conv1x1_mfma_k(const float* __restrict__ x,
    const unsigned short* __restrict__ wpack, const float* __restrict__ b0,
    float* __restrict__ x0t) {
  #define S1ROW 72
  __shared__ __align__(16) unsigned short samp1[64 * S1ROW];  // 9216 B
  int tid = threadIdx.x;
  int lane = tid & 63, q = tid >> 6;
  int pixbase = blockIdx.x * 64;
  int hwb = pixbase & (HWv - 1);
  int b = pixbase >> 14;
  {
    unsigned short tmp[16];
    #pragma unroll
    for (int i = 0; i < 16; i++) {
      int ci = q * 16 + i;
      tmp[i] = f2bf(x[((size_t)b * CCH + ci) * HWv + hwb + lane]);
    }
    #pragma unroll
    for (int i = 0; i < 2; i++)
      *(bf16x8*)(samp1 + lane * S1ROW + q * 16 + i * 8) = *(bf16x8*)(tmp + i * 8);
  }
  __syncthreads();
  f32x4 acc[4] = {{0,0,0,0},{0,0,0,0},{0,0,0,0},{0,0,0,0}};
  int g = lane >> 4;
  const bf16x8* bp = (const bf16x8*)wpack + (size_t)(q * 2) * 64 + lane;
  #pragma unroll
  for (int s = 0; s < 2; s++) {
    bf16x8 bf = bp[(size_t)s * 64];
    #pragma unroll
    for (int t = 0; t < 4; t++) {
      bf16x8 a = *(const bf16x8*)(samp1 + (t * 16 + (lane & 15)) * S1ROW + g * 8 + s * 32);
      acc[t] = __builtin_amdgcn_mfma_f32_16x16x32_bf16(a, bf, acc[t], 0, 0, 0);
    }
  }
  int co = q * 16 + (lane & 15);
  float bv = b0[co];
  float* dst = x0t + ((size_t)b * HWv + hwb + g * 4) * 64 + co;
  #pragma unroll
  for (int t = 0; t < 4; t++)
    #pragma unroll
    for (int r = 0; r < 4; r++)
      dst[(size_t)(t * 16 + r) * 64] = acc[t][r] + bv;
}

// ==== om conv MFMA: 16 px x 32 co(27), K=1152 tap-major, NHWC in/out =======
__global__ __launch_bounds__(256) void om_mfma_k(const float* __restrict__ x0t,
    const float* __restrict__ yt, const unsigned short* __restrict__ wpack,
    const float* __restrict__ bias, float* __restrict__ om_t) {
  __shared__ __align__(16) unsigned short samp[PPB * OMROW];  // 37,120 B
  __shared__ __align__(16) float red[2 * 64 * 4];             // 2 KB
  unsigned int* samp32 = (unsigned int*)samp;
  int tid = threadIdx.x;
  int pixbase = blockIdx.x * PPB;
  int hwb = pixbase & (HWv - 1);
  int b = pixbase >> 14;
  int h = hwb >> 7, wb = hwb & 127;

  // stage: half-wave per (pix, tap, 64ch-half); float2 loads, u32 stores
  {
    int lane2 = tid & 31, hw8 = tid >> 5;
    const float* x0b = x0t + (size_t)b * HWv * 64 + lane2 * 2;
    const float* ytb = yt  + (size_t)b * HWv * 64 + lane2 * 2;
    #pragma unroll 4
    for (int i = 0; i < 36; i++) {
      int u = hw8 + 8 * i;                 // 0..287
      int half = u & 1;
      int t9 = u >> 1;                     // 0..143
      int kk = t9 % 9, pix = t9 / 9;
      int hh = h - 1 + kk / 3;
      int ww = wb + pix - 1 + kk % 3;
      float2 v = {0.f, 0.f};
      if ((unsigned)hh < HH && (unsigned)ww < WWD) {
        const float* sp = (half ? ytb : x0b) + (size_t)(hh * WWD + ww) * 64;
        v = *(const float2*)sp;
      }
      samp32[pix * (OMROW / 2) + kk * 64 + half * 32 + lane2] = f2bf2(v.x, v.y);
    }
  }
  __syncthreads();

  int lane = tid & 63, q = tid >> 6;
  int cohalf = q & 1, khalf = q >> 1;
  f32x4 acc = {0.f, 0.f, 0.f, 0.f};
  const unsigned short* arow = samp + (lane & 15) * OMROW + khalf * 576 + (lane >> 4) * 8;
  const bf16x8* bp = (const bf16x8*)wpack + (size_t)(cohalf * OMKS + khalf * 18) * 64 + lane;
  #pragma unroll
  for (int s = 0; s < 18; s++) {
    bf16x8 a = *(const bf16x8*)(arow + s * 32);
    bf16x8 bf = bp[(size_t)s * 64];
    acc = __builtin_amdgcn_mfma_f32_16x16x32_bf16(a, bf, acc, 0, 0, 0);
  }
  if (khalf) {
    *(f32x4*)(red + (cohalf * 64 + lane) * 4) = acc;
  }
  __syncthreads();
  if (!khalf) {
    f32x4 o = *(const f32x4*)(red + (cohalf * 64 + lane) * 4);
    int co = cohalf * 16 + (lane & 15);
    if (co < 27) {
      float bv = bias[co];
      int pixr = (lane >> 4) * 4;
      size_t ob_ = ((size_t)b * HWv + hwb + pixr) * OMC + co;
      om_t[ob_]           = acc[0] + o[0] + bv;
      om_t[ob_ + OMC]     = acc[1] + o[1] + bv;
      om_t[ob_ + 2 * OMC] = acc[2] + o[2] + bv;
      om_t[ob_ + 3 * OMC] = acc[3] + o[3] + bv;
    }
  }
}

// ============ unified MFMA conv, K=576 tap-major ==========================
// MODE 0: deform (in=yt NHWC, om_t NHWC, res=x0t NHWC) -> ob NHWC
// MODE 1: conv3x3+leaky (in=ob NHWC) -> z1 NHWC
// MODE 2: conv3x3+res(ob NHWC) (in=z1 NHWC) -> out NCHW (final)
template <int MODE>
__global__ __launch_bounds__(256) void mconv_k(const float* __restrict__ in,
    const float* __restrict__ omt, const float* __restrict__ res,
    const unsigned short* __restrict__ wpack, const float* __restrict__ bias,
    float* __restrict__ outp) {
  __shared__ __align__(16) unsigned short samp[PPB * SROW];   // 18,688 B
  unsigned int* samp32 = (unsigned int*)samp;
  int tid = threadIdx.x;
  int pixbase = blockIdx.x * PPB;
  int hwb = pixbase & (HWv - 1);
  int b = pixbase >> 14;
  int h = hwb >> 7, wb = hwb & 127;

  if (MODE == 0) {
    __shared__ float prm[6][PPB * KK];
    if (tid < PPB * KK) {
      int pix = tid / KK, k = tid % KK;
      const float* omb = omt + ((size_t)b * HWv + hwb + pix) * OMC;
      float dy = omb[2 * k];
      float dx = omb[2 * k + 1];
      float mk = 2.f / (1.f + expf(-omb[18 + k]));
      float ys = (float)(h - 1 + k / 3) + dy;
      float xs = (float)(wb + pix - 1 + k % 3) + dx;
      float y0f = floorf(ys), x0f = floorf(xs);
      float ty = ys - y0f, tx = xs - x0f;
      prm[0][tid] = y0f;
      prm[1][tid] = x0f;
      prm[2][tid] = (1.f - ty) * (1.f - tx) * mk;
      prm[3][tid] = (1.f - ty) * tx * mk;
      prm[4][tid] = ty * (1.f - tx) * mk;
      prm[5][tid] = ty * tx * mk;
    }
    __syncthreads();
    int lane2 = tid & 31, hw8 = tid >> 5;
    const float* ytb = in + (size_t)b * HWv * 64 + lane2 * 2;
    #pragma unroll 2
    for (int i = 0; i < 18; i++) {
      int u = hw8 + 8 * i;                 // 0..143
      int k = u % 9, pix = u / 9;
      int e = pix * KK + k;
      int yi = (int)prm[0][e], xi = (int)prm[1][e];
      float w00 = prm[2][e], w01 = prm[3][e];
      float w10 = prm[4][e], w11 = prm[5][e];
      bool y0v = (unsigned)yi < HH, y1v = (unsigned)(yi + 1) < HH;
      bool x0v = (unsigned)xi < WWD, x1v = (unsigned)(xi + 1) < WWD;
      long base = (long)yi * WWD + xi;
      float vx = 0.f, vy = 0.f;
      if (y0v && x0v) { float2 s = *(const float2*)(ytb + base * 64);
        vx = fmaf(s.x, w00, vx); vy = fmaf(s.y, w00, vy); }
      if (y0v && x1v) { float2 s = *(const float2*)(ytb + (base + 1) * 64);
        vx = fmaf(s.x, w01, vx); vy = fmaf(s.y, w01, vy); }
      if (y1v && x0v) { float2 s = *(const float2*)(ytb + (base + WWD) * 64);
        vx = fmaf(s.x, w10, vx); vy = fmaf(s.y, w10, vy); }
      if (y1v && x1v) { float2 s = *(const float2*)(ytb + (base + WWD + 1) * 64);
        vx = fmaf(s.x, w11, vx); vy = fmaf(s.y, w11, vy); }
      samp32[pix * (SROW / 2) + k * 32 + lane2] = f2bf2(vx, vy);
    }
  } else {
    int lane2 = tid & 31, hw8 = tid >> 5;
    const float* inb = in + (size_t)b * HWv * 64 + lane2 * 2;
    #pragma unroll 2
    for (int i = 0; i < 18; i++) {
      int u = hw8 + 8 * i;                 // 0..143
      int kk = u % 9, pix = u / 9;
      int hh = h - 1 + kk / 3;
      int ww = wb + pix - 1 + kk % 3;
      float2 v = {0.f, 0.f};
      if ((unsigned)hh < HH && (unsigned)ww < WWD)
        v = *(const float2*)(inb + (size_t)(hh * WWD + ww) * 64);
      samp32[pix * (SROW / 2) + kk * 32 + lane2] = f2bf2(v.x, v.y);
    }
  }
  __syncthreads();

  // ---- MFMA: out[16 pix][16 co-quadrant] ----
  int lane = tid & 63;
  int q = tid >> 6;
  f32x4 acc = {0.f, 0.f, 0.f, 0.f};
  const unsigned short* arow = samp + (lane & 15) * SROW + (lane >> 4) * 8;
  const bf16x8* bp = (const bf16x8*)wpack + (size_t)(q * KSTEP) * 64 + lane;
  #pragma unroll
  for (int s = 0; s < KSTEP; s++) {
    bf16x8 a = *(const bf16x8*)(arow + s * 32);
    bf16x8 bf = bp[(size_t)s * 64];
    acc = __builtin_amdgcn_mfma_f32_16x16x32_bf16(a, bf, acc, 0, 0, 0);
  }

  int co = q * 16 + (lane & 15);
  int pixr = (lane >> 4) * 4;
  float bv = bias[co];
  if (MODE == 2) {
    size_t rbase = ((size_t)b * HWv + hwb + pixr) * 64 + co;
    float4 r = {acc[0] + bv + res[rbase],       acc[1] + bv + res[rbase + 64],
                acc[2] + bv + res[rbase + 128], acc[3] + bv + res[rbase + 192]};
    *(float4*)(outp + ((size_t)b * CCH + co) * HWv + hwb + pixr) = r;
  } else if (MODE == 0) {
    size_t obase = ((size_t)b * HWv + hwb + pixr) * 64 + co;
    outp[obase]       = acc[0] + bv + res[obase];
    outp[obase + 64]  = acc[1] + bv + res[obase + 64];
    outp[obase + 128] = acc[2] + bv + res[obase + 128];
    outp[obase + 192] = acc[3] + bv + res[obase + 192];
  } else {
    size_t obase = ((size_t)b * HWv + hwb + pixr) * 64 + co;
    #pragma unroll
    for (int r = 0; r < 4; r++) {
      float v = acc[r] + bv;
      outp[obase + (size_t)r * 64] = v >= 0.f ? v : 0.2f * v;
    }
  }
}

extern "C" void kernel_launch(void* const* d_in, const int* in_sizes, int n_in,
                              void* d_out, int out_size, void* d_ws, size_t ws_size,
                              hipStream_t stream) {
  const float* x    = (const float*)d_in[0];
  const float* y    = (const float*)d_in[1];
  const float* w0   = (const float*)d_in[2];
  const float* b0   = (const float*)d_in[3];
  const float* w_om = (const float*)d_in[4];
  const float* b_om = (const float*)d_in[5];
  const float* w_dc = (const float*)d_in[6];
  const float* b_dc = (const float*)d_in[7];
  const float* w1   = (const float*)d_in[8];
  const float* b1   = (const float*)d_in[9];
  const float* w2   = (const float*)d_in[10];
  const float* b2   = (const float*)d_in[11];
  float* out = (float*)d_out;

  const size_t NFULL = (size_t)BB * CCH * HWv;   // 2,097,152 floats
  const size_t NOMT  = (size_t)BB * HWv * OMC;   // 1,048,576
  const size_t NPACK = 4 * KSTEP * 64 * 8;       // 36,864 bf16
  const size_t NPACKOM = 2 * OMKS * 64 * 8;      // 36,864
  const size_t NPACK1  = 4 * 2 * 64 * 8;         //  4,096
  float* x0t = (float*)d_ws;
  float* omt = x0t + NFULL;
  float* ob  = omt + NOMT;
  float* z1  = ob + NFULL;
  float* yt  = z1;                               // alias: yt dead before z1 written
  unsigned short* pk_dc = (unsigned short*)(z1 + NFULL);
  unsigned short* pk_w1 = pk_dc + NPACK;
  unsigned short* pk_w2 = pk_w1 + NPACK;
  unsigned short* pk_om = pk_w2 + NPACK;
  unsigned short* pk_0  = pk_om + NPACKOM;

  pack_tap_k<4, KSTEP, 64, 64><<<(int)(NPACK / 256), 256, 0, stream>>>(w_dc, pk_dc);
  pack_tap_k<4, KSTEP, 64, 64><<<(int)(NPACK / 256), 256, 0, stream>>>(w1, pk_w1);
  pack_tap_k<4, KSTEP, 64, 64><<<(int)(NPACK / 256), 256, 0, stream>>>(w2, pk_w2);
  pack_tap_k<2, OMKS, 27, 128><<<(int)(NPACKOM / 256), 256, 0, stream>>>(w_om, pk_om);
  pack_k<4, 2, 64, 64><<<(int)(NPACK1 / 256), 256, 0, stream>>>(w0, pk_0);

  // 0. y -> NHWC (into z1's buffer; consumed before z1 is written)
  transpose_yk<<<(int)((size_t)BB * HWv / 64), 256, 0, stream>>>(y, yt);
  // 1. conv1x1 -> x0t (NHWC)
  conv1x1_mfma_k<<<(int)((size_t)BB * HWv / 64), 256, 0, stream>>>(x, pk_0, b0, x0t);

  const int mblocks = (int)((size_t)BB * HWv / PPB);  // 2048
  // 2. offset/mask conv -> om_t (NHWC, stride 32)
  om_mfma_k<<<mblocks, 256, 0, stream>>>(x0t, yt, pk_om, b_om, omt);
  // 3. deformable conv + x0t residual -> ob (NHWC)
  mconv_k<0><<<mblocks, 256, 0, stream>>>(yt, omt, x0t, pk_dc, b_dc, ob);
  // 4. conv w1 + leaky -> z1 (NHWC)
  mconv_k<1><<<mblocks, 256, 0, stream>>>(ob, nullptr, nullptr, pk_w1, b1, z1);
  // 5. conv w2 + residual ob -> out (NCHW final)
  mconv_k<2><<<mblocks, 256, 0, stream>>>(z1, nullptr, ob, pk_w2, b2, out);
}